// Round 13
// baseline (393.567 us; speedup 1.0000x reference)
//
#include <hip/hip_runtime.h>
#include <stdint.h>

// Problem: B=8, S=1024, V=8192, D=256. out[b,s,:] = (x[b,s,:] @ E)*16 + pos[s,:]*any(x[b,s,:])
// GEMM M=8192 K=8192 N=256, A=x (0/1 int32, 256 MB stream), B=emb (bf16 table in ws).
// R13: R12 + XCD-aware block decode (kidx = blockIdx.x & 7). Round-robin dispatch then maps
//      each kidx to one XCD, so each XCD's L2 holds only its 512 KB B-slice (L2-resident)
//      instead of the whole 4 MB table. Single-variable test of placement locality.

#define K_TOT 8192
#define D_DIM 256
#define KSPLIT 8
#define KCHUNK (K_TOT / KSPLIT)   // 1024
#define BK 64                     // ints of k per tile
#define TROWS 64                  // rows per block
#define NTILES (KCHUNK / BK)      // 16
#define PART_STRIDE (8192u * 256u)  // elements per partial

typedef short  short8  __attribute__((ext_vector_type(8)));
typedef float  floatx4 __attribute__((ext_vector_type(4)));
typedef int    intx4   __attribute__((ext_vector_type(4)));
typedef unsigned short ushort4v __attribute__((ext_vector_type(4)));

union S8U { intx4 i; short8 s; };

// ws layout: [0,4MB)    bf16 B-table [c=16][kb=256][lane=64][8]
//            [4,36MB)   bf16 partials [KSPLIT=8][8192][256]
//            [36MB,..)  int rs_part [KSPLIT=8][8192]
#define WS_PART_OFF (4u * 1024u * 1024u)
#define WS_RS_OFF   (36u * 1024u * 1024u)

__device__ __forceinline__ unsigned int bf16_rne(float f) {
    unsigned int u = __float_as_uint(f);
    u += 0x7fffu + ((u >> 16) & 1u);
    return u >> 16;
}

// aux=2 -> NT: read-once stream, minimize L2 pollution
__device__ __forceinline__ void load_lds16_nt(const int* g, int* l) {
    __builtin_amdgcn_global_load_lds((const __attribute__((address_space(1))) unsigned int*)g,
                                     (__attribute__((address_space(3))) unsigned int*)l,
                                     16, 0, 2);
}

// ---- emb [8192][256] fp32 -> fragment-major bf16 table, scaled by sqrt(D)=16 ----
// wsBf[((c*256+kb)*64+l)*8+jj] = bf16(emb[kb*32+(l>>4)*8+jj][c*16+(l&15)] * 16)
__global__ __launch_bounds__(256) void prep_kernel(const float* __restrict__ emb,
                                                   unsigned short* __restrict__ wsBf) {
    int gid = blockIdx.x * 256 + threadIdx.x;
    int l  = gid & 63;
    int kb = (gid >> 6) & 255;
    int c  = gid >> 14;
    int d  = c * 16 + (l & 15);
    int v0 = kb * 32 + (l >> 4) * 8;
    const float* src = emb + (size_t)v0 * D_DIM + d;
    intx4 q;
#pragma unroll
    for (int p = 0; p < 4; ++p) {
        unsigned int u0 = bf16_rne(src[(size_t)(2 * p) * D_DIM] * 16.0f);
        unsigned int u1 = bf16_rne(src[(size_t)(2 * p + 1) * D_DIM] * 16.0f);
        q[p] = (int)(u0 | (u1 << 16));
    }
    *(intx4*)(wsBf + (size_t)gid * 8) = q;
}

// ---- GEMM: 1-D grid 1024: kidx = bid & 7 (XCD-pinned), mb = bid >> 3. 64 rows/block. ----
// LDS tile image: granule G (16B), G = row*16 + slot; holds A granule slot^(row&7) of row.
// Staging (DMA-legal): wave w, load p covers dest granules [w*256+p*64, +64) =
//   rows w*16+p*4 .. +3 (4 rows x 16 slots), dest = base + lane*16B.
// K-tiles visited rotated: p(tl) = (tl+phase) & 15.
__global__ __launch_bounds__(256, 4) void gemm_kernel(const int* __restrict__ x,
                                                      const unsigned short* __restrict__ wsBf,
                                                      unsigned short* __restrict__ part,
                                                      int* __restrict__ rsp) {
    __shared__ int Al[2][4096];    // 2 x 16 KB (64 rows x 64 ints)

    const int bid   = blockIdx.x;
    const int kidx  = bid & 7;                  // XCD-pinned K-slice (round-robin dispatch)
    const int mb    = bid >> 3;
    const int m0    = mb * TROWS;
    const int kbeg  = kidx * KCHUNK;
    const int phase = (mb * 7 + kidx * 9) & (NTILES - 1);
    const int t     = threadIdx.x;
    const int wave  = t >> 6, lane = t & 63;
    const int quad  = lane >> 4, rl = lane & 15;
    const int sx    = rl & 7;                   // read-side swizzle key

    // staging map: wave w, load p: row = w*16 + p*4 + (lane>>4), slot = lane&15,
    // source granule = slot ^ (row&7), dest int offset = w*1024 + p*256 + lane*4.
    const int srow0 = wave * 16 + (lane >> 4);
    const int slt   = lane & 15;
    const int* gsrc[4];
#pragma unroll
    for (int p = 0; p < 4; ++p) {
        int rw = srow0 + p * 4;
        gsrc[p] = x + (size_t)(m0 + rw) * K_TOT + kbeg + ((slt ^ (rw & 7)) * 4);
    }
    const int dofs = wave * 1024 + lane * 4;

    floatx4 acc[4][4];
#pragma unroll
    for (int i = 0; i < 4; ++i)
#pragma unroll
        for (int j = 0; j < 4; ++j) acc[i][j] = (floatx4){0.f, 0.f, 0.f, 0.f};
    int rp[4] = {0, 0, 0, 0};

    const int kbase = kidx * (KCHUNK / 32);     // global 32-int k-block base

    // prologue: stage tile p(0) into buf 0
#pragma unroll
    for (int p = 0; p < 4; ++p)
        load_lds16_nt(gsrc[p] + phase * BK, &Al[0][dofs + p * 256]);

    for (int tl = 0; tl < NTILES; ++tl) {
        const int pcur = (tl + phase) & (NTILES - 1);
        __syncthreads();                         // buf[tl&1] ready; prior readers done
        if (tl + 1 < NTILES) {
            const int pnx = (tl + 1 + phase) & (NTILES - 1);
            int* dst = &Al[(tl + 1) & 1][dofs];
#pragma unroll
            for (int p = 0; p < 4; ++p)
                load_lds16_nt(gsrc[p] + pnx * BK, dst + p * 256);
        }
        const int* buf = &Al[tl & 1][0];

#pragma unroll
        for (int s = 0; s < 2; ++s) {            // two k32 steps per tile
            const int kb = kbase + pcur * 2 + s;

            short8 bf[4];                        // B: cacheable, L2-resident per XCD now
#pragma unroll
            for (int j = 0; j < 4; ++j)
                bf[j] = ((const S8U*)(wsBf + ((size_t)((wave * 4 + j) * 256 + kb) * 64 + lane) * 8))->s;

            short8 af[4];
#pragma unroll
            for (int i = 0; i < 4; ++i) {
                int row  = i * 16 + rl;
                int rowb = row * 64;
                int g0   = s * 8 + quad * 2;             // granules for k..k+3, k+4..k+7
                intx4 v0 = *(const intx4*)(buf + rowb + ((g0 ^ sx) * 4));
                intx4 v1 = *(const intx4*)(buf + rowb + (((g0 + 1) ^ sx) * 4));
                int p0 = v0[0] | (v0[1] << 16);
                int p1 = v0[2] | (v0[3] << 16);
                int p2 = v1[0] | (v1[1] << 16);
                int p3 = v1[2] | (v1[3] << 16);
                if (wave == 0) rp[i] += p0 + p1 + p2 + p3;
                S8U u;
                u.i[0] = p0 * 0x3F80;                    // pair*0x3F80 -> two bf16 (1.0/0.0)
                u.i[1] = p1 * 0x3F80;
                u.i[2] = p2 * 0x3F80;
                u.i[3] = p3 * 0x3F80;
                af[i] = u.s;
            }

#pragma unroll
            for (int i = 0; i < 4; ++i)
#pragma unroll
                for (int j = 0; j < 4; ++j)
                    acc[i][j] = __builtin_amdgcn_mfma_f32_16x16x32_bf16(af[i], bf[j], acc[i][j], 0, 0, 0);
        }
    }

    // row-sums (wave 0's lanes jointly saw every (row,k) of the chunk): reduce quads, store
    if (wave == 0) {
#pragma unroll
        for (int i = 0; i < 4; ++i) {
            int cnt = (rp[i] & 0xFFFF) + ((unsigned)rp[i] >> 16);
            cnt += __shfl_xor(cnt, 16);
            cnt += __shfl_xor(cnt, 32);
            if (quad == 0) rsp[(size_t)kidx * 8192 + m0 + i * 16 + rl] = cnt;
        }
    }

    // partial store as bf16 (quantization ~0.06 absmax worst case vs 1.91 threshold).
    // C/D layout col=lane&15, row=quad*4+reg (m89-verified). NT stores.
    unsigned short* pk = part + (size_t)kidx * PART_STRIDE;
#pragma unroll
    for (int i = 0; i < 4; ++i) {
#pragma unroll
        for (int j = 0; j < 4; ++j) {
            int col = wave * 64 + j * 16 + rl;
#pragma unroll
            for (int r = 0; r < 4; ++r) {
                int row = m0 + i * 16 + quad * 4 + r;
                __builtin_nontemporal_store((unsigned short)bf16_rne(acc[i][j][r]),
                                            &pk[(size_t)row * D_DIM + col]);
            }
        }
    }
}

// ---- reduce: out = sum_k bf16(part[k]) + pos * (sum_k rs[k] > 0) ----
__global__ __launch_bounds__(256) void reduce_kernel(const unsigned short* __restrict__ part,
                                                     const int* __restrict__ rsp,
                                                     const float* __restrict__ pos,
                                                     float* __restrict__ out) {
    int gid = blockIdx.x * 256 + threadIdx.x;    // 512K threads, 4 elements each
    size_t base = (size_t)gid * 4;
    int row = gid >> 6;
    floatx4 a = {0.f, 0.f, 0.f, 0.f};
    int rsum = 0;
#pragma unroll
    for (int k = 0; k < KSPLIT; ++k) {
        ushort4v u = *(const ushort4v*)(part + (size_t)k * PART_STRIDE + base);
#pragma unroll
        for (int e = 0; e < 4; ++e)
            a[e] += __uint_as_float((unsigned int)u[e] << 16);
        rsum += rsp[(size_t)k * 8192 + row];
    }
    if (rsum > 0) {
        int s = row & 1023;                      // m = b*1024 + s
        int col = (gid & 63) * 4;
        a += *(const floatx4*)(pos + (size_t)s * D_DIM + col);
    }
    *(floatx4*)(out + base) = a;
}

extern "C" void kernel_launch(void* const* d_in, const int* in_sizes, int n_in,
                              void* d_out, int out_size, void* d_ws, size_t ws_size,
                              hipStream_t stream) {
    const int*   x   = (const int*)d_in[0];     // [8,1024,8192] int32
    const float* emb = (const float*)d_in[1];   // [8192,256] fp32
    const float* pos = (const float*)d_in[2];   // [1,1024,256] fp32
    float*       out = (float*)d_out;           // [8,1024,256] fp32

    unsigned short* wsBf = (unsigned short*)d_ws;
    unsigned short* part = (unsigned short*)((char*)d_ws + WS_PART_OFF);
    int*            rsp  = (int*)((char*)d_ws + WS_RS_OFF);

    prep_kernel<<<dim3(1024), dim3(256), 0, stream>>>(emb, wsBf);
    gemm_kernel<<<dim3(1024), dim3(256), 0, stream>>>(x, wsBf, part, rsp);
    reduce_kernel<<<dim3(2048), dim3(256), 0, stream>>>(part, rsp, pos, out);
}